// Round 8
// baseline (32.547 us; speedup 1.0000x reference)
//
#include <hip/hip_runtime.h>

#define JITTER 1e-5f

__device__ __forceinline__ float rl(float v, int l) {
    return __uint_as_float(__builtin_amdgcn_readlane(__float_as_uint(v), l));
}
__device__ __forceinline__ float fast_rcp(float v) {
#if __has_builtin(__builtin_amdgcn_rcpf)
    return __builtin_amdgcn_rcpf(v);     // 1-ulp-ish; fine vs 9.4e-2 threshold
#else
    return 1.0f / v;
#endif
}

// ---------------------------------------------------------------------------
// One kernel, 256 blocks x 512 threads (2 particles/block).
// Wave 0 solves (C + jitter*I) a = e for BOTH particles with the round-7
// VERIFIED row-per-lane register Gauss-Jordan (absmax 4.9e-4), rescheduled
// to be I-cache resident: instead of 64 fully-unrolled steps (~40 KB of
// straight-line code streaming through a 32 KB L1I), a runtime panel loop
// (p = 0..3, #pragma unroll 1) runs 16 static steps then rotates the
// register window row[c] <- row[c+16] (48 movs). Register indices stay
// compile-time static; only the readlane LANE index k = p*16+i is runtime
// (SGPR lane index is legal). Dead high registers in later panels receive
// harmless updates (stale finite matrix values). Hot body ~13 KB -> L1I.
//   per step (global k):  piv = rl(reg[i], k);  fr = (lane==k)?0:reg[i]*rcp;
//                         reg[c] -= fr * rl(reg[c], k)  for c in [i,64)
//                         b -= fr * rl(b, k);  dg = (lane==k)?piv:dg
//   final: a = b / dg.
// Epilogue = the round-5/7 verified code, unchanged.
// ---------------------------------------------------------------------------
__global__ __launch_bounds__(512) void diag_sgp_fused3(
    const float* __restrict__ x,        // (n,8)
    const float* __restrict__ y,        // (n,32)
    const float* __restrict__ z,        // (n,2048)
    const float* __restrict__ gamma,    // (n,2048)
    const float* __restrict__ inducing, // (64,8)
    const float* __restrict__ Kmat,     // (32,32)
    const float* __restrict__ pvar,
    const float* __restrict__ pls,
    const float* __restrict__ pnoise,
    float* __restrict__ out,            // [m_new (n,2048) | g (n,2048)]
    int n_total)
{
    const int tid = threadIdx.x;
    const int n0  = blockIdx.x * 2;
    const int t8  = tid & 255;           // thread within particle
    const int h   = tid >> 8;            // particle half (0/1)

    // ---- prefetch HBM-heavy operands immediately ----
    const size_t base = (size_t)(n0 + h) * 2048 + t8 * 8;
    const float4 g0 = *reinterpret_cast<const float4*>(gamma + base);
    const float4 g1 = *reinterpret_cast<const float4*>(gamma + base + 4);
    const float4 zv0 = *reinterpret_cast<const float4*>(z + base);
    const float4 zv1 = *reinterpret_cast<const float4*>(z + base + 4);

    __shared__ float Zt[8 * 64];                   // inducing transposed
    __shared__ float Kl[32 * 33];                  // K, pitch 33
    __shared__ float xl[2][8], yl[2][32];
    __shared__ float e_sh[2][64];
    __shared__ __align__(16) float a_sh[2][64];
    __shared__ float t_sh[2][32], rc[2][32], rd[2][32], s1s[2][32], s2s[2][32];
    __shared__ float Bsh[2];

    Zt[(tid & 7) * 64 + (tid >> 3)] = inducing[tid & 511];   // 512 elems
    for (int i = tid; i < 1024; i += 512)
        Kl[(i >> 5) * 33 + (i & 31)] = Kmat[i];
    if (tid < 16) xl[tid >> 3][tid & 7]  = x[n0 * 8 + tid];   // contiguous
    if (tid < 64) yl[tid >> 5][tid & 31] = y[n0 * 32 + tid];  // contiguous
    const float var = pvar[0], ls = pls[0], nv = pnoise[0];
    const float sc = 0.5f / (ls * ls);
    __syncthreads();                               // B1

    // ================= wave-0 register GJ solve (row-per-lane) ===========
    if (tid < 64) {
        const int lane = tid;
        float zc[8];
#pragma unroll
        for (int dd = 0; dd < 8; ++dd) zc[dd] = Zt[dd * 64 + lane];

        // build rows: row[c] = M[lane][c] (run-once code; evicted later)
        float row[64];
#pragma unroll
        for (int c = 0; c < 64; ++c) {
            float sq = 0.f;
#pragma unroll
            for (int dd = 0; dd < 8; ++dd) {
                const float df = zc[dd] - rl(zc[dd], c);
                sq = fmaf(df, df, sq);
            }
            const float v = __expf(-sq * sc);
            row[c] = (lane == c) ? v + JITTER : v;
        }
        // RHS (lane-local), both particles
        float b0, b1;
        {
            float sq0 = 0.f, sq1 = 0.f;
#pragma unroll
            for (int dd = 0; dd < 8; ++dd) {
                const float d0 = xl[0][dd] - zc[dd]; sq0 = fmaf(d0, d0, sq0);
                const float d1 = xl[1][dd] - zc[dd]; sq1 = fmaf(d1, d1, sq1);
            }
            b0 = __expf(-sq0 * sc);
            b1 = __expf(-sq1 * sc);
        }
        e_sh[0][lane] = b0;
        e_sh[1][lane] = b1;

        float dg = 1.f;
#pragma unroll 1                         // keep the panel loop ROLLED (I-cache)
        for (int p = 0; p < 4; ++p) {
            const int k0 = p * 16;
#pragma unroll                           // 16 static steps
            for (int i = 0; i < 16; ++i) {
                const int k = k0 + i;              // runtime lane index: OK
                const float piv  = rl(row[i], k);  // M[k][k] (uniform)
                const float rinv = fast_rcp(piv);
                const float fr   = (lane == k) ? 0.f : row[i] * rinv;
#pragma unroll
                for (int c = i; c < 64; ++c) {     // static reg indices
                    const float s_c = rl(row[c], k);
                    row[c] = fmaf(-fr, s_c, row[c]);
                }
                const float bk0 = rl(b0, k);
                const float bk1 = rl(b1, k);
                b0 = fmaf(-fr, bk0, b0);
                b1 = fmaf(-fr, bk1, b1);
                dg = (lane == k) ? piv : dg;
            }
            // rotate window: global col (c+16(p+1)) -> reg c
#pragma unroll
            for (int c = 0; c < 48; ++c) row[c] = row[c + 16];
        }
        a_sh[0][lane] = b0 / dg;
        a_sh[1][lane] = b1 / dg;
    }
    __syncthreads();                               // B2

    // ================= verified epilogue, 2 particles =================
    if (t8 < 64) {                                 // waves 0 & 4: B reduce
        float v = e_sh[h][t8] * a_sh[h][t8];
        for (int off = 32; off; off >>= 1) v += __shfl_down(v, off);
        if (t8 == 0) Bsh[h] = var * (1.f - v);
    }

    // t[j] partials via 8-lane shfl tree
    const int jrow = t8 >> 3;
    float ga[8] = {g0.x, g0.y, g0.z, g0.w, g1.x, g1.y, g1.z, g1.w};
    const int ab = (t8 & 7) * 8;
    const float4 a0 = *reinterpret_cast<const float4*>(&a_sh[h][ab]);
    const float4 a1 = *reinterpret_cast<const float4*>(&a_sh[h][ab + 4]);
    const float as[8] = {a0.x, a0.y, a0.z, a0.w, a1.x, a1.y, a1.z, a1.w};

    float pt = 0.f;
#pragma unroll
    for (int e = 0; e < 8; ++e) pt += as[e] * as[e] * ga[e];
    pt += __shfl_xor(pt, 1);
    pt += __shfl_xor(pt, 2);
    pt += __shfl_xor(pt, 4);
    if ((t8 & 7) == 0) t_sh[h][jrow] = pt;
    __syncthreads();                               // B3

    if (t8 < 32) {                                 // c, d per output dim
        float acc = 0.f;
        for (int jj = 0; jj < 32; ++jj) {
            const float kv = Kl[t8 * 33 + jj];
            acc += kv * kv * t_sh[h][jj];
        }
        const float ci = Bsh[h] * Kl[t8 * 34] + nv;
        const float di = acc + ci;
        rc[h][t8] = yl[h][t8] / ci;
        rd[h][t8] = 1.0f / di;
    }
    __syncthreads();                               // B4

    if (t8 < 32) {                                 // s1, s2 per j
        float sa = 0.f, sb = 0.f;
        for (int i = 0; i < 32; ++i) {
            const float kv = Kl[i * 33 + t8];
            sa += kv * rc[h][i];
            sb += kv * kv * rd[h][i];
        }
        s1s[h][t8] = sa;
        s2s[h][t8] = sb;
    }
    __syncthreads();                               // B5

    const float zv[8] = {zv0.x, zv0.y, zv0.z, zv0.w, zv1.x, zv1.y, zv1.z, zv1.w};
    const float s1j = s1s[h][jrow], s2j = s2s[h][jrow];
    float mn[8], gg[8];
#pragma unroll
    for (int e = 0; e < 8; ++e) {
        const float ge = ga[e];
        const float am = as[e];
        const float gm = ge * am;
        const float gv = ge - gm * gm * s2j;
        gg[e] = gv;
        mn[e] = gv * (zv[e] / ge + am * s1j);
    }

    float* o_m = out + base;
    float* o_g = out + (size_t)n_total * 2048 + base;
    *reinterpret_cast<float4*>(o_m)     = make_float4(mn[0], mn[1], mn[2], mn[3]);
    *reinterpret_cast<float4*>(o_m + 4) = make_float4(mn[4], mn[5], mn[6], mn[7]);
    *reinterpret_cast<float4*>(o_g)     = make_float4(gg[0], gg[1], gg[2], gg[3]);
    *reinterpret_cast<float4*>(o_g + 4) = make_float4(gg[4], gg[5], gg[6], gg[7]);
}

extern "C" void kernel_launch(void* const* d_in, const int* in_sizes, int n_in,
                              void* d_out, int out_size, void* d_ws, size_t ws_size,
                              hipStream_t stream)
{
    const float* x        = (const float*)d_in[0];
    const float* y        = (const float*)d_in[1];
    const float* z        = (const float*)d_in[2];
    const float* gamma    = (const float*)d_in[3];
    const float* inducing = (const float*)d_in[4];
    const float* Kmat     = (const float*)d_in[5];
    const float* pvar     = (const float*)d_in[6];
    const float* pls      = (const float*)d_in[7];
    const float* pnoise   = (const float*)d_in[8];
    float* out = (float*)d_out;

    const int n = in_sizes[0] / 8;       // 512
    diag_sgp_fused3<<<dim3(n / 2), dim3(512), 0, stream>>>(
        x, y, z, gamma, inducing, Kmat, pvar, pls, pnoise, out, n);
}

// Round 9
// 32.536 us; speedup vs baseline: 1.0003x; 1.0003x over previous
//
#include <hip/hip_runtime.h>

#define JITTER 1e-5f

__device__ __forceinline__ float rl(float v, int l) {
    return __uint_as_float(__builtin_amdgcn_readlane(__float_as_uint(v), l));
}
__device__ __forceinline__ float fast_rcp(float v) {
#if __has_builtin(__builtin_amdgcn_rcpf)
    return __builtin_amdgcn_rcpf(v);
#else
    return 1.0f / v;
#endif
}

// ---------------------------------------------------------------------------
// Kernel 1: single-wave register Gauss-Jordan on the SHARED matrix
// C + jitter*I (row-per-lane, the round-7/8 verified recurrence), recording
// the elimination "tape": per step k the factor vector fr (lane-local) and
// finally 1/diag. The tape is all any particle needs: the RHS update
//   b -= fr[k] * readlane(b, k)   (k = 0..63)
// applied in the same order reproduces the verified solve exactly.
// tape[lane][k] layout (row-contiguous per lane) so kernel 2 can load each
// lane's 64 factors as 16 dwordx4 into statically-indexed registers.
// ---------------------------------------------------------------------------
__global__ __launch_bounds__(64) void kzz_tape_kernel(
    const float* __restrict__ inducing,  // (64,8)
    const float* __restrict__ pls,
    float* __restrict__ tape,            // (64,64): tape[lane][k] = fr
    float* __restrict__ invd)            // (64):   1/diag
{
    const int lane = threadIdx.x;
    const float ls = pls[0];
    const float sc = 0.5f / (ls * ls);

    float zc[8];
    {
        const float4 za = *reinterpret_cast<const float4*>(inducing + lane * 8);
        const float4 zb = *reinterpret_cast<const float4*>(inducing + lane * 8 + 4);
        zc[0] = za.x; zc[1] = za.y; zc[2] = za.z; zc[3] = za.w;
        zc[4] = zb.x; zc[5] = zb.y; zc[6] = zb.z; zc[7] = zb.w;
    }

    float row[64];
#pragma unroll
    for (int c = 0; c < 64; ++c) {
        float sq = 0.f;
#pragma unroll
        for (int dd = 0; dd < 8; ++dd) {
            const float df = zc[dd] - rl(zc[dd], c);
            sq = fmaf(df, df, sq);
        }
        const float v = __expf(-sq * sc);
        row[c] = (lane == c) ? v + JITTER : v;
    }

    float fr_hist[64];
    float dg = 1.f;
#pragma unroll
    for (int k = 0; k < 64; ++k) {
        const float piv  = rl(row[k], k);
        const float rinv = fast_rcp(piv);
        const float fr   = (lane == k) ? 0.f : row[k] * rinv;
        fr_hist[k] = fr;
#pragma unroll
        for (int c = k; c < 64; ++c) {
            const float s_c = rl(row[c], k);
            row[c] = fmaf(-fr, s_c, row[c]);
        }
        dg = (lane == k) ? piv : dg;
    }

    invd[lane] = 1.0f / dg;
    float* tp = tape + lane * 64;
#pragma unroll
    for (int u = 0; u < 16; ++u)
        *reinterpret_cast<float4*>(tp + u * 4) =
            make_float4(fr_hist[u * 4 + 0], fr_hist[u * 4 + 1],
                        fr_hist[u * 4 + 2], fr_hist[u * 4 + 3]);
}

// ---------------------------------------------------------------------------
// Kernel 2: 256 blocks x 512 threads (2 particles/block) — the round-7
// VERIFIED kernel (absmax 4.9e-4) with the per-block matrix elimination
// replaced by the 64-step tape replay (identical factors, identical order).
// ---------------------------------------------------------------------------
__global__ __launch_bounds__(512) void diag_sgp_replay(
    const float* __restrict__ x,        // (n,8)
    const float* __restrict__ y,        // (n,32)
    const float* __restrict__ z,        // (n,2048)
    const float* __restrict__ gamma,    // (n,2048)
    const float* __restrict__ inducing, // (64,8)
    const float* __restrict__ Kmat,     // (32,32)
    const float* __restrict__ pvar,
    const float* __restrict__ pls,
    const float* __restrict__ pnoise,
    const float* __restrict__ tape,     // (64,64)
    const float* __restrict__ invd,     // (64)
    float* __restrict__ out,            // [m_new (n,2048) | g (n,2048)]
    int n_total)
{
    const int tid = threadIdx.x;
    const int n0  = blockIdx.x * 2;
    const int t8  = tid & 255;           // thread within particle
    const int h   = tid >> 8;            // particle half (0/1)

    // ---- prefetch HBM-heavy operands immediately ----
    const size_t base = (size_t)(n0 + h) * 2048 + t8 * 8;
    const float4 g0 = *reinterpret_cast<const float4*>(gamma + base);
    const float4 g1 = *reinterpret_cast<const float4*>(gamma + base + 4);
    const float4 zv0 = *reinterpret_cast<const float4*>(z + base);
    const float4 zv1 = *reinterpret_cast<const float4*>(z + base + 4);

    __shared__ float Zt[8 * 64];                   // inducing transposed
    __shared__ float Kl[32 * 33];                  // K, pitch 33
    __shared__ float xl[2][8], yl[2][32];
    __shared__ float e_sh[2][64];
    __shared__ __align__(16) float a_sh[2][64];
    __shared__ float t_sh[2][32], rc[2][32], rd[2][32], s1s[2][32], s2s[2][32];
    __shared__ float Bsh[2];

    Zt[(tid & 7) * 64 + (tid >> 3)] = inducing[tid & 511];   // 512 elems
    for (int i = tid; i < 1024; i += 512)
        Kl[(i >> 5) * 33 + (i & 31)] = Kmat[i];
    if (tid < 16) xl[tid >> 3][tid & 7]  = x[n0 * 8 + tid];   // contiguous
    if (tid < 64) yl[tid >> 5][tid & 31] = y[n0 * 32 + tid];  // contiguous
    const float var = pvar[0], ls = pls[0], nv = pnoise[0];
    const float sc = 0.5f / (ls * ls);
    __syncthreads();                               // B1

    // ================= wave-0 tape replay solve =================
    if (tid < 64) {
        const int lane = tid;
        // issue tape + invd loads first (L2 after block 0; hide under e-build)
        const float* tp = tape + lane * 64;
        float fr[64];
#pragma unroll
        for (int u = 0; u < 16; ++u) {
            const float4 t = *reinterpret_cast<const float4*>(tp + u * 4);
            fr[u * 4 + 0] = t.x; fr[u * 4 + 1] = t.y;
            fr[u * 4 + 2] = t.z; fr[u * 4 + 3] = t.w;
        }
        const float idg = invd[lane];

        float zc[8];
#pragma unroll
        for (int dd = 0; dd < 8; ++dd) zc[dd] = Zt[dd * 64 + lane];

        float b0, b1;
        {
            float sq0 = 0.f, sq1 = 0.f;
#pragma unroll
            for (int dd = 0; dd < 8; ++dd) {
                const float d0 = xl[0][dd] - zc[dd]; sq0 = fmaf(d0, d0, sq0);
                const float d1 = xl[1][dd] - zc[dd]; sq1 = fmaf(d1, d1, sq1);
            }
            b0 = __expf(-sq0 * sc);
            b1 = __expf(-sq1 * sc);
        }
        e_sh[0][lane] = b0;
        e_sh[1][lane] = b1;

#pragma unroll
        for (int k = 0; k < 64; ++k) {             // the verified recurrence
            const float bk0 = rl(b0, k);
            const float bk1 = rl(b1, k);
            b0 = fmaf(-fr[k], bk0, b0);
            b1 = fmaf(-fr[k], bk1, b1);
        }
        a_sh[0][lane] = b0 * idg;
        a_sh[1][lane] = b1 * idg;
    }
    __syncthreads();                               // B2

    // ================= verified epilogue, 2 particles =================
    if (t8 < 64) {                                 // waves 0 & 4: B reduce
        float v = e_sh[h][t8] * a_sh[h][t8];
        for (int off = 32; off; off >>= 1) v += __shfl_down(v, off);
        if (t8 == 0) Bsh[h] = var * (1.f - v);
    }

    // t[j] partials via 8-lane shfl tree
    const int jrow = t8 >> 3;
    float ga[8] = {g0.x, g0.y, g0.z, g0.w, g1.x, g1.y, g1.z, g1.w};
    const int ab = (t8 & 7) * 8;
    const float4 a0 = *reinterpret_cast<const float4*>(&a_sh[h][ab]);
    const float4 a1 = *reinterpret_cast<const float4*>(&a_sh[h][ab + 4]);
    const float as[8] = {a0.x, a0.y, a0.z, a0.w, a1.x, a1.y, a1.z, a1.w};

    float pt = 0.f;
#pragma unroll
    for (int e = 0; e < 8; ++e) pt += as[e] * as[e] * ga[e];
    pt += __shfl_xor(pt, 1);
    pt += __shfl_xor(pt, 2);
    pt += __shfl_xor(pt, 4);
    if ((t8 & 7) == 0) t_sh[h][jrow] = pt;
    __syncthreads();                               // B3

    if (t8 < 32) {                                 // c, d per output dim
        float acc = 0.f;
        for (int jj = 0; jj < 32; ++jj) {
            const float kv = Kl[t8 * 33 + jj];
            acc += kv * kv * t_sh[h][jj];
        }
        const float ci = Bsh[h] * Kl[t8 * 34] + nv;
        const float di = acc + ci;
        rc[h][t8] = yl[h][t8] / ci;
        rd[h][t8] = 1.0f / di;
    }
    __syncthreads();                               // B4

    if (t8 < 32) {                                 // s1, s2 per j
        float sa = 0.f, sb = 0.f;
        for (int i = 0; i < 32; ++i) {
            const float kv = Kl[i * 33 + t8];
            sa += kv * rc[h][i];
            sb += kv * kv * rd[h][i];
        }
        s1s[h][t8] = sa;
        s2s[h][t8] = sb;
    }
    __syncthreads();                               // B5

    const float zv[8] = {zv0.x, zv0.y, zv0.z, zv0.w, zv1.x, zv1.y, zv1.z, zv1.w};
    const float s1j = s1s[h][jrow], s2j = s2s[h][jrow];
    float mn[8], gg[8];
#pragma unroll
    for (int e = 0; e < 8; ++e) {
        const float ge = ga[e];
        const float am = as[e];
        const float gm = ge * am;
        const float gv = ge - gm * gm * s2j;
        gg[e] = gv;
        mn[e] = gv * (zv[e] / ge + am * s1j);
    }

    float* o_m = out + base;
    float* o_g = out + (size_t)n_total * 2048 + base;
    *reinterpret_cast<float4*>(o_m)     = make_float4(mn[0], mn[1], mn[2], mn[3]);
    *reinterpret_cast<float4*>(o_m + 4) = make_float4(mn[4], mn[5], mn[6], mn[7]);
    *reinterpret_cast<float4*>(o_g)     = make_float4(gg[0], gg[1], gg[2], gg[3]);
    *reinterpret_cast<float4*>(o_g + 4) = make_float4(gg[4], gg[5], gg[6], gg[7]);
}

extern "C" void kernel_launch(void* const* d_in, const int* in_sizes, int n_in,
                              void* d_out, int out_size, void* d_ws, size_t ws_size,
                              hipStream_t stream)
{
    const float* x        = (const float*)d_in[0];
    const float* y        = (const float*)d_in[1];
    const float* z        = (const float*)d_in[2];
    const float* gamma    = (const float*)d_in[3];
    const float* inducing = (const float*)d_in[4];
    const float* Kmat     = (const float*)d_in[5];
    const float* pvar     = (const float*)d_in[6];
    const float* pls      = (const float*)d_in[7];
    const float* pnoise   = (const float*)d_in[8];
    float* out  = (float*)d_out;
    float* tape = (float*)d_ws;                    // 16 KB
    float* invd = (float*)d_ws + 64 * 64;          // 256 B

    const int n = in_sizes[0] / 8;       // 512

    kzz_tape_kernel<<<dim3(1), dim3(64), 0, stream>>>(inducing, pls, tape, invd);
    diag_sgp_replay<<<dim3(n / 2), dim3(512), 0, stream>>>(
        x, y, z, gamma, inducing, Kmat, pvar, pls, pnoise, tape, invd, out, n);
}